// Round 7
// baseline (292.811 us; speedup 1.0000x reference)
//
#include <hip/hip_runtime.h>

// CornerActivationB: ARITY=2, GROUPS=512, OUT_DIM=16, BATCH=8192, ACT_FACTOR=1
//
// Math: the 3-point hat-weight contraction against lo/mid/hi expanded params
// collapses exactly to bilinear interpolation over the 4 original corners:
//   a = (clip(x0,-1,1)+1)/2 ; b = (clip(x1,-1,1)+1)/2
//   out[d] = (1-a)(1-b) P[g,0,d] + (1-a)b P[g,1,d] + a(1-b) P[g,2,d] + ab P[g,3,d]
//
// Structure: P cached in REGISTERS (16 VGPRs/thread), block covers 64 groups
// x 32 batch rows. R7: software-pipelined — each 8-row chunk issues all 8
// nontemporal X loads first (8 outstanding/wave to cover ~900cy HBM latency),
// then computes + nontemporal-stores. R6 profile put the kernel at ~3.9 TB/s
// effective (latency-bound, only 4 loads in flight) vs 6.2 TB/s fill ceiling.

#define BATCH   8192
#define GROUPS  512
#define OUT_DIM 16
#define GCHUNK  64      // groups per block (256 threads / 4 quads)
#define BITER   32      // batch rows per block
#define CHUNK   8       // rows per load/compute phase

typedef float v4f __attribute__((ext_vector_type(4)));
typedef float v2f __attribute__((ext_vector_type(2)));

__global__ __launch_bounds__(256) void corner_act_kernel(
    const float* __restrict__ X,    // [BATCH, GROUPS*2]
    const float* __restrict__ P,    // [GROUPS, 4, OUT_DIM]
    float* __restrict__ out)        // [BATCH, GROUPS*OUT_DIM]
{
    const int t  = threadIdx.x;
    const int q  = t & 3;                       // which vec4 of OUT_DIM
    const int g  = blockIdx.x * GCHUNK + (t >> 2);

    // hoist this thread's 4 corner vectors into registers (once per block)
    const v4f* p = (const v4f*)P + g * 16 + q;
    const v4f p0 = p[0];     // corner (lo,lo)
    const v4f p1 = p[4];     // corner (lo,hi)
    const v4f p2 = p[8];     // corner (hi,lo)
    const v4f p3 = p[12];    // corner (hi,hi)

    // X row stride: 1024 floats = 512 v2f.  Out row stride: 8192 floats = 2048 v4f.
    const int b0 = blockIdx.y * BITER;
    const v2f* __restrict__ Xv = (const v2f*)X + g + (size_t)b0 * 512;
    v4f* __restrict__ Ov = (v4f*)out + blockIdx.x * 256 + t + (size_t)b0 * 2048;

    for (int c = 0; c < BITER / CHUNK; ++c) {
        v2f xs[CHUNK];
        #pragma unroll
        for (int j = 0; j < CHUNK; ++j)
            xs[j] = __builtin_nontemporal_load(Xv + (size_t)j * 512);

        #pragma unroll
        for (int j = 0; j < CHUNK; ++j) {
            const float a  = (fminf(fmaxf(xs[j].x, -1.0f), 1.0f) + 1.0f) * 0.5f;
            const float bb = (fminf(fmaxf(xs[j].y, -1.0f), 1.0f) + 1.0f) * 0.5f;
            const float w00 = (1.0f - a) * (1.0f - bb);
            const float w01 = (1.0f - a) * bb;
            const float w10 = a * (1.0f - bb);
            const float w11 = a * bb;
            const v4f o = w00 * p0 + w01 * p1 + w10 * p2 + w11 * p3;
            __builtin_nontemporal_store(o, Ov + (size_t)j * 2048);
        }

        Xv += CHUNK * 512;
        Ov += CHUNK * 2048;
    }
}

extern "C" void kernel_launch(void* const* d_in, const int* in_sizes, int n_in,
                              void* d_out, int out_size, void* d_ws, size_t ws_size,
                              hipStream_t stream) {
    const float* X = (const float*)d_in[0];   // BATCH * GROUPS*2 fp32
    const float* P = (const float*)d_in[1];   // GROUPS * 4 * OUT_DIM fp32
    float* out = (float*)d_out;               // BATCH * GROUPS*OUT_DIM fp32

    dim3 grid(GROUPS / GCHUNK, BATCH / BITER);   // (8, 256) = 2048 blocks
    corner_act_kernel<<<grid, dim3(256), 0, stream>>>(X, P, out);
}